// Round 5
// baseline (111.034 us; speedup 1.0000x reference)
//
#include <hip/hip_runtime.h>

#define OUT_UNITS 128

// ---------------- Kernel 1: CSR row pointers from sorted COO rows ------------
__global__ void build_row_starts(const int* __restrict__ rows,
                                 int* __restrict__ row_start,
                                 int nnz, int n_rows) {
    int k = blockIdx.x * blockDim.x + threadIdx.x;
    if (k >= nnz) return;
    int cur = rows[k];
    if (k == 0) {
        for (int r = 0; r <= cur; ++r) row_start[r] = 0;
    } else {
        int prev = rows[k - 1];
        for (int r = prev + 1; r <= cur; ++r) row_start[r] = k;
    }
    if (k == nnz - 1) {
        for (int r = cur + 1; r <= n_rows; ++r) row_start[r] = nnz;
    }
}

__device__ __forceinline__ float bc_f(float v, int j) {
    return __uint_as_float(__builtin_amdgcn_readlane(__float_as_uint(v), j));
}

// ---------------- Kernel 2: 4 waves/block, one row per wave ------------------
// Per 16-nnz group: readlane puts each col in an SGPR; gather address is
// SGPR base (w + c*512, scalar pipe) + lane*8 VGPR offset -> saddr-form
// global_load_dwordx2. Explicit wbuf[16] forces 16 independent gathers
// (8 KB) in flight per wave before the first waitcnt. Groups are padded to
// 16 with (valid col, v=0) so remainder == hot path.
__global__ __launch_bounds__(256)
void spmm_row_wave(const float* __restrict__ vals,
                   const float* __restrict__ w,
                   const int* __restrict__ cols,
                   const int* __restrict__ row_start,
                   float* __restrict__ out,
                   int n_rows) {
    const int wave = threadIdx.x >> 6;
    const int r    = blockIdx.x * 4 + wave;
    if (r >= n_rows) return;

    const int start = row_start[r];
    const int end   = row_start[r + 1];
    const int lane  = threadIdx.x & 63;
    const char* __restrict__ wb = (const char*)w;
    const size_t loff = (size_t)(lane << 3);  // lane*8 bytes: 64 lanes = 512B row

    float2 acc0 = make_float2(0.f, 0.f);
    float2 acc1 = make_float2(0.f, 0.f);

    for (int base = start; base < end; base += 64) {
        const int navail = min(64, end - base);
        // padded lanes: valid col (base), zero value -> contribute nothing
        int   c_l = (lane < navail) ? cols[base + lane] : cols[base];
        float v_l = (lane < navail) ? vals[base + lane] : 0.f;
        const int ngroups = (navail + 15) >> 4;

        for (int g = 0; g < ngroups; ++g) {  // g wave-uniform
            float2 wbuf[16];
#pragma unroll
            for (int j = 0; j < 16; ++j) {
                int c = __builtin_amdgcn_readlane(c_l, g * 16 + j);  // SGPR
                wbuf[j] = *(const float2*)(wb + (((size_t)(unsigned)c) << 9) + loff);
            }
#pragma unroll
            for (int j = 0; j < 16; j += 2) {
                float va = bc_f(v_l, g * 16 + j);
                float vb = bc_f(v_l, g * 16 + j + 1);
                acc0.x = fmaf(va, wbuf[j].x, acc0.x);
                acc0.y = fmaf(va, wbuf[j].y, acc0.y);
                acc1.x = fmaf(vb, wbuf[j + 1].x, acc1.x);
                acc1.y = fmaf(vb, wbuf[j + 1].y, acc1.y);
            }
        }
    }

    float2 acc = make_float2(acc0.x + acc1.x, acc0.y + acc1.y);
    ((float2*)(out + (size_t)r * OUT_UNITS))[lane] = acc;
}

extern "C" void kernel_launch(void* const* d_in, const int* in_sizes, int n_in,
                              void* d_out, int out_size, void* d_ws, size_t ws_size,
                              hipStream_t stream) {
    const float* vals = (const float*)d_in[0];
    const float* w    = (const float*)d_in[1];
    const int*   rows = (const int*)d_in[2];
    const int*   cols = (const int*)d_in[3];
    float* out = (float*)d_out;

    const int nnz    = in_sizes[0];
    const int n_rows = out_size / OUT_UNITS;  // 16384

    int* row_start = (int*)d_ws;  // (n_rows + 1) ints

    build_row_starts<<<(nnz + 255) / 256, 256, 0, stream>>>(rows, row_start, nnz, n_rows);
    spmm_row_wave<<<(n_rows + 3) / 4, 256, 0, stream>>>(vals, w, cols, row_start, out, n_rows);
}

// Round 6
// 110.860 us; speedup vs baseline: 1.0016x; 1.0016x over previous
//
#include <hip/hip_runtime.h>

#define OUT_UNITS 128

// ---------------- Kernel 1: CSR row pointers from sorted COO rows ------------
__global__ void build_row_starts(const int* __restrict__ rows,
                                 int* __restrict__ row_start,
                                 int nnz, int n_rows) {
    int k = blockIdx.x * blockDim.x + threadIdx.x;
    if (k >= nnz) return;
    int cur = rows[k];
    if (k == 0) {
        for (int r = 0; r <= cur; ++r) row_start[r] = 0;
    } else {
        int prev = rows[k - 1];
        for (int r = prev + 1; r <= cur; ++r) row_start[r] = k;
    }
    if (k == nnz - 1) {
        for (int r = cur + 1; r <= n_rows; ++r) row_start[r] = nnz;
    }
}

__device__ __forceinline__ float bc_f(float v, int j) {
    return __uint_as_float(__builtin_amdgcn_readlane(__float_as_uint(v), j));
}

// ---------------- Kernel 2: 4 waves/block, one row per wave ------------------
// 16-deep register pipeline of w-row gathers. __launch_bounds__(256, 4)
// gives the allocator a 128-VGPR budget so all 16 float2 results stay live
// (round 5 ran at VGPR=28 -> MLP collapsed to ~1, ~475 cy/gather serial).
// readlane puts each col in an SGPR -> saddr-form global_load_dwordx2 with
// lane*8 voffset. Groups padded to 16 with (valid col, v=0).
__global__ __launch_bounds__(256, 4)
void spmm_row_wave(const float* __restrict__ vals,
                   const float* __restrict__ w,
                   const int* __restrict__ cols,
                   const int* __restrict__ row_start,
                   float* __restrict__ out,
                   int n_rows) {
    const int wave = threadIdx.x >> 6;
    const int r    = blockIdx.x * 4 + wave;
    if (r >= n_rows) return;

    const int start = row_start[r];
    const int end   = row_start[r + 1];
    const int lane  = threadIdx.x & 63;
    const char* __restrict__ wb = (const char*)w;
    const size_t loff = (size_t)(lane << 3);  // lane*8 bytes: 64 lanes = 512B row

    float2 acc0 = make_float2(0.f, 0.f);
    float2 acc1 = make_float2(0.f, 0.f);
    float2 acc2 = make_float2(0.f, 0.f);
    float2 acc3 = make_float2(0.f, 0.f);

    for (int base = start; base < end; base += 64) {
        const int navail = min(64, end - base);
        // padded lanes: valid col (base), zero value -> contribute nothing
        int   c_l = (lane < navail) ? cols[base + lane] : cols[base];
        float v_l = (lane < navail) ? vals[base + lane] : 0.f;
        const int ngroups = (navail + 15) >> 4;

        for (int g = 0; g < ngroups; ++g) {  // g wave-uniform
            float2 wbuf[16];
            // ---- issue phase: 16 independent gathers, no consumer between ----
#pragma unroll
            for (int j = 0; j < 16; ++j) {
                int c = __builtin_amdgcn_readlane(c_l, g * 16 + j);  // SGPR
                wbuf[j] = *(const float2*)(wb + (((size_t)(unsigned)c) << 9) + loff);
            }
            // ---- consume phase: in issue order, 4 independent fma chains ----
#pragma unroll
            for (int j = 0; j < 16; j += 4) {
                float va = bc_f(v_l, g * 16 + j);
                float vb = bc_f(v_l, g * 16 + j + 1);
                float vc = bc_f(v_l, g * 16 + j + 2);
                float vd = bc_f(v_l, g * 16 + j + 3);
                acc0.x = fmaf(va, wbuf[j].x, acc0.x);
                acc0.y = fmaf(va, wbuf[j].y, acc0.y);
                acc1.x = fmaf(vb, wbuf[j + 1].x, acc1.x);
                acc1.y = fmaf(vb, wbuf[j + 1].y, acc1.y);
                acc2.x = fmaf(vc, wbuf[j + 2].x, acc2.x);
                acc2.y = fmaf(vc, wbuf[j + 2].y, acc2.y);
                acc3.x = fmaf(vd, wbuf[j + 3].x, acc3.x);
                acc3.y = fmaf(vd, wbuf[j + 3].y, acc3.y);
            }
        }
    }

    float2 acc = make_float2((acc0.x + acc1.x) + (acc2.x + acc3.x),
                             (acc0.y + acc1.y) + (acc2.y + acc3.y));
    ((float2*)(out + (size_t)r * OUT_UNITS))[lane] = acc;
}

extern "C" void kernel_launch(void* const* d_in, const int* in_sizes, int n_in,
                              void* d_out, int out_size, void* d_ws, size_t ws_size,
                              hipStream_t stream) {
    const float* vals = (const float*)d_in[0];
    const float* w    = (const float*)d_in[1];
    const int*   rows = (const int*)d_in[2];
    const int*   cols = (const int*)d_in[3];
    float* out = (float*)d_out;

    const int nnz    = in_sizes[0];
    const int n_rows = out_size / OUT_UNITS;  // 16384

    int* row_start = (int*)d_ws;  // (n_rows + 1) ints

    build_row_starts<<<(nnz + 255) / 256, 256, 0, stream>>>(rows, row_start, nnz, n_rows);
    spmm_row_wave<<<(n_rows + 3) / 4, 256, 0, stream>>>(vals, w, cols, row_start, out, n_rows);
}